// Round 7
// baseline (407.322 us; speedup 1.0000x reference)
//
#include <hip/hip_runtime.h>

// ---------------------------------------------------------------------------
// GCN forward, pull-based + fused. A(HW) = (AH)W:
//   per layer one kernel: gather A·H rows into LDS (packed {src,w} edge
//   records, two rows interleaved per thread = 8 independent load chains),
//   then 128x128 matvec with W staged in two 32 KiB halves (48 KiB LDS/block
//   -> 3 blocks/CU). Layer 4's matvec commutes past the mean-pool:
//   out = mean(agg4)·(W4·Wlin) + (b4·Wlin + blin), and layer-4 gather is
//   fused with the segmented mean-pool (batch sorted).
// ---------------------------------------------------------------------------

__global__ void k_count(const int* __restrict__ dstv, int E, int* __restrict__ cnt) {
    int e = blockIdx.x * blockDim.x + threadIdx.x;
    if (e < E) atomicAdd(&cnt[dstv[e]], 1);
}

// scan1 also emits dinv (cnt still pristine here)
__global__ void k_scan1(const int* __restrict__ cnt, int N,
                        int* __restrict__ rowptr, int* __restrict__ bsums,
                        float* __restrict__ dinv) {
    __shared__ int sh[256];
    const int t = threadIdx.x;
    const int i = blockIdx.x * 256 + t;
    const int v = (i < N) ? cnt[i] : 0;
    if (i < N) dinv[i] = 1.0f / sqrtf((float)(v + 1));  // +1 self loop
    sh[t] = v;
    __syncthreads();
    for (int off = 1; off < 256; off <<= 1) {
        int add = (t >= off) ? sh[t - off] : 0;
        __syncthreads();
        sh[t] += add;
        __syncthreads();
    }
    if (i < N) rowptr[i] = sh[t] - v;
    if (t == 255) bsums[blockIdx.x] = sh[255];
}

__global__ void k_scan2(int* __restrict__ bsums, int nb) {
    __shared__ int sh[256];
    const int t = threadIdx.x;
    const int v = (t < nb) ? bsums[t] : 0;
    sh[t] = v;
    __syncthreads();
    for (int off = 1; off < 256; off <<= 1) {
        int add = (t >= off) ? sh[t - off] : 0;
        __syncthreads();
        sh[t] += add;
        __syncthreads();
    }
    if (t < nb) bsums[t] = sh[t] - v;
}

__global__ void k_scan3(int* __restrict__ rowptr, const int* __restrict__ bsums,
                        int* __restrict__ cnt, int N, int E) {
    const int i = blockIdx.x * blockDim.x + threadIdx.x;
    if (i < N) {
        rowptr[i] += bsums[i >> 8];
        cnt[i] = 0;                            // becomes fill cursor
    }
    if (i == 0) rowptr[N] = E;
}

// packed edge record: .x = src index (bit pattern), .y = dinv[src]*dinv[dst]
__global__ void k_fill(const int* __restrict__ srcv, const int* __restrict__ dstv,
                       const int* __restrict__ rowptr, int* __restrict__ cur,
                       const float* __restrict__ dinv,
                       float2* __restrict__ csr_pack, int E) {
    int e = blockIdx.x * blockDim.x + threadIdx.x;
    if (e < E) {
        const int d = dstv[e];
        const int s = srcv[e];
        const int slot = atomicAdd(&cur[d], 1);
        const int p = rowptr[d] + slot;
        float2 rec;
        rec.x = __int_as_float(s);
        rec.y = dinv[s] * dinv[d];
        csr_pack[p] = rec;
    }
    if (e == 0) {
        float2 z; z.x = __int_as_float(0); z.y = 0.f;
        csr_pack[E] = z;   // sentinel
    }
}

__global__ void k_bounds(const int* __restrict__ batch, int N, int G,
                         int* __restrict__ start) {
    const int g = blockIdx.x * blockDim.x + threadIdx.x;
    if (g > G) return;
    int lo = 0, hi = N;
    while (lo < hi) {
        const int mid = (lo + hi) >> 1;
        if (batch[mid] < g) lo = mid + 1; else hi = mid;
    }
    start[g] = lo;
}

// Wc = W4 @ Wlin (128 x T), bc = b4 @ Wlin + blin (T)
__global__ void k_combine(const float* __restrict__ W4, const float* __restrict__ Wlin,
                          const float* __restrict__ b4, const float* __restrict__ blin,
                          float* __restrict__ Wc, float* __restrict__ bc, int T) {
    const int idx = blockIdx.x * blockDim.x + threadIdx.x;
    if (idx < 128 * T) {
        const int k = idx / T, t = idx % T;
        float acc = 0.f;
        #pragma unroll 8
        for (int j = 0; j < 128; ++j)
            acc = fmaf(W4[k * 128 + j], Wlin[j * T + t], acc);
        Wc[idx] = acc;
    }
    if (idx < T) {
        float acc = blin[idx];
        #pragma unroll 8
        for (int j = 0; j < 128; ++j)
            acc = fmaf(b4[j], Wlin[j * T + idx], acc);
        bc[idx] = acc;
    }
}

__device__ __forceinline__ void fma4(float4& acc, float s, const float4& w) {
    acc.x = fmaf(s, w.x, acc.x);
    acc.y = fmaf(s, w.y, acc.y);
    acc.z = fmaf(s, w.z, acc.z);
    acc.w = fmaf(s, w.w, acc.w);
}

// Gather aggregated rows n0 AND n1, interleaved 4-wide each: 8 independent
// {record -> row} load chains in flight. Edge weights are precomputed, so
// no shuffles and no per-edge dinv reads. Exhausted/invalid slots carry
// weight 0 and (masked) skip their loads.
__device__ __forceinline__ void gather_pair2(
    int n0, int n1, int v0, int v1,
    const float* __restrict__ Hin,
    const int* __restrict__ rowptr, const float2* __restrict__ pk,
    const float* __restrict__ dinv, int lane,
    float4& r0, float4& r1)
{
    const int nc0 = v0 ? n0 : 0;
    const int nc1 = v1 ? n1 : 0;
    const float dn0 = v0 ? dinv[nc0] : 0.f;
    const float dn1 = v1 ? dinv[nc1] : 0.f;
    int c0 = rowptr[nc0];
    int c1 = rowptr[nc1];
    const int e0 = v0 ? rowptr[nc0 + 1] : c0;
    const int e1 = v1 ? rowptr[nc1 + 1] : c1;

    const float4 s0v = *(const float4*)(Hin + (size_t)nc0 * 128 + 4 * lane);
    const float4 s1v = *(const float4*)(Hin + (size_t)nc1 * 128 + 4 * lane);
    const float sw0 = dn0 * dn0, sw1 = dn1 * dn1;
    float4 p0 = make_float4(s0v.x * sw0, s0v.y * sw0, s0v.z * sw0, s0v.w * sw0);
    float4 q0 = make_float4(s1v.x * sw1, s1v.y * sw1, s1v.z * sw1, s1v.w * sw1);
    float4 p1 = make_float4(0.f, 0.f, 0.f, 0.f);
    float4 q1 = make_float4(0.f, 0.f, 0.f, 0.f);

    const float2 zrec = make_float2(__int_as_float(0), 0.f);

    while (c0 < e0 || c1 < e1) {
        // 8 record loads (uniform per 32-lane group, hardware broadcast)
        const float2 ra0 = (c0 + 0 < e0) ? pk[c0 + 0] : zrec;
        const float2 ra1 = (c0 + 1 < e0) ? pk[c0 + 1] : zrec;
        const float2 ra2 = (c0 + 2 < e0) ? pk[c0 + 2] : zrec;
        const float2 ra3 = (c0 + 3 < e0) ? pk[c0 + 3] : zrec;
        const float2 rb0 = (c1 + 0 < e1) ? pk[c1 + 0] : zrec;
        const float2 rb1 = (c1 + 1 < e1) ? pk[c1 + 1] : zrec;
        const float2 rb2 = (c1 + 2 < e1) ? pk[c1 + 2] : zrec;
        const float2 rb3 = (c1 + 3 < e1) ? pk[c1 + 3] : zrec;
        // 8 independent row loads
        const float4 va0 = *(const float4*)(Hin + (size_t)__float_as_int(ra0.x) * 128 + 4 * lane);
        const float4 va1 = *(const float4*)(Hin + (size_t)__float_as_int(ra1.x) * 128 + 4 * lane);
        const float4 va2 = *(const float4*)(Hin + (size_t)__float_as_int(ra2.x) * 128 + 4 * lane);
        const float4 va3 = *(const float4*)(Hin + (size_t)__float_as_int(ra3.x) * 128 + 4 * lane);
        const float4 vb0 = *(const float4*)(Hin + (size_t)__float_as_int(rb0.x) * 128 + 4 * lane);
        const float4 vb1 = *(const float4*)(Hin + (size_t)__float_as_int(rb1.x) * 128 + 4 * lane);
        const float4 vb2 = *(const float4*)(Hin + (size_t)__float_as_int(rb2.x) * 128 + 4 * lane);
        const float4 vb3 = *(const float4*)(Hin + (size_t)__float_as_int(rb3.x) * 128 + 4 * lane);
        fma4(p0, ra0.y, va0); fma4(p1, ra1.y, va1);
        fma4(p0, ra2.y, va2); fma4(p1, ra3.y, va3);
        fma4(q0, rb0.y, vb0); fma4(q1, rb1.y, vb1);
        fma4(q0, rb2.y, vb2); fma4(q1, rb3.y, vb3);
        c0 += 4; c1 += 4;
    }
    p0.x += p1.x; p0.y += p1.y; p0.z += p1.z; p0.w += p1.w;
    q0.x += q1.x; q0.y += q1.y; q0.z += q1.z; q0.w += q1.w;
    r0 = p0;
    r1 = q0;
}

// Fused layer: Hout[n] = relu( (A·Hin)[n] @ W + bias ). One 32-row tile/block.
// W staged in two 64x128 halves; accumulators live across both passes.
__global__ __launch_bounds__(512, 6) void k_layer(
    const float* __restrict__ Hin, const float* __restrict__ W,
    const float* __restrict__ bias,
    const int* __restrict__ rowptr, const float2* __restrict__ csr_pack,
    const float* __restrict__ dinv,
    float* __restrict__ Hout, int N)
{
    __shared__ float Wl[64 * 128];    // 32 KiB: half of W [k][c]
    __shared__ float hl[32 * 128];    // 16 KiB: 32 aggregated rows
    const int tid = threadIdx.x;
    for (int i = tid; i < 2048; i += 512)
        ((float4*)Wl)[i] = ((const float4*)W)[i];          // rows 0..63

    const int lane = tid & 31;
    const int grp  = tid >> 5;        // 0..15
    const int rowBase = blockIdx.x << 5;

    const int n0 = rowBase + grp;
    const int n1 = rowBase + grp + 16;
    const int v0 = n0 < N, v1 = n1 < N;
    float4 g0, g1;
    gather_pair2(n0, n1, v0, v1, Hin, rowptr, csr_pack, dinv, lane, g0, g1);
    if (v0) *(float4*)(hl + grp * 128 + 4 * lane) = g0;
    if (v1) *(float4*)(hl + (grp + 16) * 128 + 4 * lane) = g1;
    __syncthreads();   // hl + Wl(half 0) ready

    float4 a0 = make_float4(0.f, 0.f, 0.f, 0.f);
    float4 a1 = make_float4(0.f, 0.f, 0.f, 0.f);
    // pass 0: k = 0..63
    #pragma unroll 4
    for (int kq = 0; kq < 16; ++kq) {
        const float4 h0 = *(const float4*)(hl + grp * 128 + 4 * kq);
        const float4 h1 = *(const float4*)(hl + (grp + 16) * 128 + 4 * kq);
        const float4* wp = ((const float4*)Wl) + (4 * kq) * 32 + lane;
        const float4 w0 = wp[0];
        const float4 w1 = wp[32];
        const float4 w2 = wp[64];
        const float4 w3 = wp[96];
        fma4(a0, h0.x, w0); fma4(a0, h0.y, w1); fma4(a0, h0.z, w2); fma4(a0, h0.w, w3);
        fma4(a1, h1.x, w0); fma4(a1, h1.y, w1); fma4(a1, h1.z, w2); fma4(a1, h1.w, w3);
    }
    __syncthreads();   // pass-0 Wl reads done
    for (int i = tid; i < 2048; i += 512)
        ((float4*)Wl)[i] = ((const float4*)(W + 64 * 128))[i];  // rows 64..127
    __syncthreads();   // Wl(half 1) ready
    // pass 1: k = 64..127
    #pragma unroll 4
    for (int kq = 0; kq < 16; ++kq) {
        const float4 h0 = *(const float4*)(hl + grp * 128 + 64 + 4 * kq);
        const float4 h1 = *(const float4*)(hl + (grp + 16) * 128 + 64 + 4 * kq);
        const float4* wp = ((const float4*)Wl) + (4 * kq) * 32 + lane;
        const float4 w0 = wp[0];
        const float4 w1 = wp[32];
        const float4 w2 = wp[64];
        const float4 w3 = wp[96];
        fma4(a0, h0.x, w0); fma4(a0, h0.y, w1); fma4(a0, h0.z, w2); fma4(a0, h0.w, w3);
        fma4(a1, h1.x, w0); fma4(a1, h1.y, w1); fma4(a1, h1.z, w2); fma4(a1, h1.w, w3);
    }

    const float4 bv = ((const float4*)bias)[lane];
    a0.x += bv.x; a0.y += bv.y; a0.z += bv.z; a0.w += bv.w;
    a1.x += bv.x; a1.y += bv.y; a1.z += bv.z; a1.w += bv.w;
    a0.x = fmaxf(a0.x, 0.f); a0.y = fmaxf(a0.y, 0.f);
    a0.z = fmaxf(a0.z, 0.f); a0.w = fmaxf(a0.w, 0.f);
    a1.x = fmaxf(a1.x, 0.f); a1.y = fmaxf(a1.y, 0.f);
    a1.z = fmaxf(a1.z, 0.f); a1.w = fmaxf(a1.w, 0.f);
    if (v0) *(float4*)(Hout + (size_t)n0 * 128 + 4 * lane) = a0;
    if (v1) *(float4*)(Hout + (size_t)n1 * 128 + 4 * lane) = a1;
}

// Layer 4 gather fused with segmented mean-pool numerator (batch sorted).
// Each block gathers 32 consecutive rows into LDS, then reduces per spanned
// graph and atomically adds one partial per (graph, channel).
__global__ __launch_bounds__(512) void k_g4pool(
    const int* __restrict__ rowptr, const float2* __restrict__ csr_pack,
    const float* __restrict__ dinv, const float* __restrict__ Hin,
    const int* __restrict__ batch, const int* __restrict__ startv,
    float* __restrict__ pooled, int N)
{
    __shared__ float hl[32][128];   // 16 KiB gathered rows
    __shared__ float red[4][128];   // 2 KiB reduction scratch
    const int tid = threadIdx.x;
    const int lane = tid & 31;
    const int grp  = tid >> 5;      // 0..15
    const int base = blockIdx.x << 5;

    const int n0 = base + 2 * grp;
    const int n1 = n0 + 1;
    float4 r0, r1;
    gather_pair2(n0, n1, n0 < N, n1 < N, Hin, rowptr, csr_pack, dinv, lane, r0, r1);
    *(float4*)(&hl[2 * grp][4 * lane]) = r0;       // invalid rows -> zeros
    *(float4*)(&hl[2 * grp + 1][4 * lane]) = r1;
    __syncthreads();

    const int g0 = batch[base < N ? base : N - 1];
    const int g1 = batch[(base + 31) < N ? (base + 31) : N - 1];
    const int c = tid & 127;        // channel
    const int q = tid >> 7;         // 0..3
    for (int g = g0; g <= g1; ++g) {
        const int lo = max(startv[g], base);
        const int hi = min(startv[g + 1], base + 32);
        float s = 0.f;
        for (int r = lo - base + q; r < hi - base; r += 4)
            s += hl[r][c];
        red[q][c] = s;
        __syncthreads();
        if (q == 0) {
            const float tot = red[0][c] + red[1][c] + red[2][c] + red[3][c];
            atomicAdd(&pooled[(size_t)g * 128 + c], tot);
        }
        __syncthreads();
    }
}

// out[g][t] = (pooled[g]/cnt[g]) . Wc[:,t] + bc[t]
__global__ void k_final(const float* __restrict__ pooled, const int* __restrict__ startv,
                        const float* __restrict__ Wc, const float* __restrict__ bc,
                        float* __restrict__ out, int T)
{
    __shared__ float hv[128];
    const int g = blockIdx.x;
    const int c = threadIdx.x;
    const float inv = 1.0f / fmaxf((float)(startv[g + 1] - startv[g]), 1.0f);
    hv[c] = pooled[(size_t)g * 128 + c] * inv;
    __syncthreads();
    if (c < T) {
        float acc = bc[c];
        #pragma unroll
        for (int k = 0; k < 128; ++k)
            acc = fmaf(hv[k], Wc[k * T + c], acc);
        out[g * T + c] = acc;
    }
}

extern "C" void kernel_launch(void* const* d_in, const int* in_sizes, int n_in,
                              void* d_out, int out_size, void* d_ws, size_t ws_size,
                              hipStream_t stream)
{
    const float* x     = (const float*)d_in[0];
    const int*   ei    = (const int*)d_in[1];
    const int*   batch = (const int*)d_in[2];
    const float* W1    = (const float*)d_in[3];
    const float* b1    = (const float*)d_in[4];
    const float* Ws    = (const float*)d_in[5];
    const float* bs    = (const float*)d_in[6];
    const float* Wlin  = (const float*)d_in[7];
    const float* blin  = (const float*)d_in[8];
    float* out = (float*)d_out;

    const int N = in_sizes[0] / 128;
    const int E = in_sizes[1] / 2;
    const int T = in_sizes[8];           // 10
    const int G = out_size / T;          // 512

    // workspace layout (float offsets):
    float*  ws = (float*)d_ws;
    int*    cnt      = (int*)ws;                     // [N] histogram -> cursor (dead after fill)
    int*    rowptr   = (int*)(ws + 50000);           // [N+1]
    int*    bsums    = (int*)(ws + 100016);          // [256]
    int*    start    = (int*)(ws + 100272);          // [G+1]
    float2* csr_pack = (float2*)(ws + 100800);       // [E+1] packed records
    float*  dinv     = ws + 1380816;                 // [N]
    float*  bufA     = ws + 1430816;                 // [N*128]
    float*  bufB     = ws + 7830816;                 // [N*128]
    float*  pooled   = ws + 14230816;                // [G*128]
    float*  Wc       = ws + 24000;                   // reuse cnt region (dead), [128*T]
    float*  bc       = ws + 24000 + 128 * 10;        // [T]

    const int* srcs = ei;
    const int* dsts = ei + E;
    const float* W4 = Ws + 2 * 16384;
    const float* b4 = bs + 2 * 128;

    hipMemsetAsync(cnt, 0, (size_t)N * sizeof(int), stream);
    hipMemsetAsync(pooled, 0, (size_t)G * 128 * sizeof(float), stream);

    const int nb = (N + 255) / 256;
    k_count <<<(E + 255) / 256, 256, 0, stream>>>(dsts, E, cnt);
    k_scan1 <<<nb, 256, 0, stream>>>(cnt, N, rowptr, bsums, dinv);
    k_scan2 <<<1, 256, 0, stream>>>(bsums, nb);
    k_scan3 <<<nb, 256, 0, stream>>>(rowptr, bsums, cnt, N, E);
    k_fill  <<<(E + 255) / 256, 256, 0, stream>>>(srcs, dsts, rowptr, cnt, dinv, csr_pack, E);
    k_bounds<<<(G + 256) / 256, 256, 0, stream>>>(batch, N, G, start);
    // cnt region dead from here; Wc/bc overlap it (k_combine runs after k_fill)
    k_combine<<<(128 * T + 255) / 256, 256, 0, stream>>>(W4, Wlin, b4, blin, Wc, bc, T);

    const int layerBlocks = (N + 31) / 32;   // 1563, one 32-row tile each

    k_layer<<<layerBlocks, 512, 0, stream>>>(x,    W1,         b1,       rowptr, csr_pack, dinv, bufA, N);
    k_layer<<<layerBlocks, 512, 0, stream>>>(bufA, Ws,         bs,       rowptr, csr_pack, dinv, bufB, N);
    k_layer<<<layerBlocks, 512, 0, stream>>>(bufB, Ws + 16384, bs + 128, rowptr, csr_pack, dinv, bufA, N);
    // layer 4 gather fused with pool
    k_g4pool<<<layerBlocks, 512, 0, stream>>>(rowptr, csr_pack, dinv, bufA, batch, start, pooled, N);

    k_final<<<G, 128, 0, stream>>>(pooled, start, Wc, bc, out, T);
}

// Round 8
// 349.610 us; speedup vs baseline: 1.1651x; 1.1651x over previous
//
#include <hip/hip_runtime.h>

// ---------------------------------------------------------------------------
// GCN forward, pull-based + fused. A(HW) = (AH)W:
//   per layer one kernel: gather A·H rows into LDS, then 128x128 matvec with
//   W staged in two 32 KiB halves (48 KiB LDS/block -> 3 blocks/CU).
//   Gather inner loop is BRANCH-FREE: CSR rows padded to multiples of 4
//   records ({src=0,w=0} sentinels), exhausted rows redirect their chunk
//   address to a dummy zero-chunk -> 8 independent load chains per thread.
//   Layer 4's matvec commutes past the mean-pool:
//   out = mean(agg4)·(W4·Wlin) + (b4·Wlin + blin); its gather is fused with
//   the segmented mean-pool (batch sorted).
// ---------------------------------------------------------------------------

__global__ void k_count(const int* __restrict__ dstv, int E, int* __restrict__ cnt) {
    int e = blockIdx.x * blockDim.x + threadIdx.x;
    if (e < E) atomicAdd(&cnt[dstv[e]], 1);
}

// scan over PADDED counts ((deg+3)&~3); also emits dinv from raw deg
__global__ void k_scan1(const int* __restrict__ cnt, int N,
                        int* __restrict__ rowptr, int* __restrict__ bsums,
                        float* __restrict__ dinv) {
    __shared__ int sh[256];
    const int t = threadIdx.x;
    const int i = blockIdx.x * 256 + t;
    const int v = (i < N) ? cnt[i] : 0;
    const int pv = (v + 3) & ~3;
    if (i < N) dinv[i] = 1.0f / sqrtf((float)(v + 1));  // +1 self loop
    sh[t] = pv;
    __syncthreads();
    for (int off = 1; off < 256; off <<= 1) {
        int add = (t >= off) ? sh[t - off] : 0;
        __syncthreads();
        sh[t] += add;
        __syncthreads();
    }
    if (i < N) rowptr[i] = sh[t] - pv;
    if (t == 255) bsums[blockIdx.x] = sh[255];
}

__global__ void k_scan2(int* __restrict__ bsums, int nb) {
    __shared__ int sh[256];
    const int t = threadIdx.x;
    const int v = (t < nb) ? bsums[t] : 0;
    sh[t] = v;
    __syncthreads();
    for (int off = 1; off < 256; off <<= 1) {
        int add = (t >= off) ? sh[t - off] : 0;
        __syncthreads();
        sh[t] += add;
        __syncthreads();
    }
    if (t < nb) bsums[t] = sh[t] - v;
}

__global__ void k_scan3(int* __restrict__ rowptr, const int* __restrict__ bsums,
                        int* __restrict__ cnt, int N) {
    const int i = blockIdx.x * blockDim.x + threadIdx.x;
    if (i < N) {
        rowptr[i] += bsums[i >> 8];
        if (i == N - 1) rowptr[N] = rowptr[i] + ((cnt[i] + 3) & ~3);
        cnt[i] = 0;                            // becomes fill cursor
    }
}

// packed edge record: .x = src index (bit pattern), .y = dinv[src]*dinv[dst]
// pad slots (memset to 0) = {src 0, weight 0.0}
__global__ void k_fill(const int* __restrict__ srcv, const int* __restrict__ dstv,
                       const int* __restrict__ rowptr, int* __restrict__ cur,
                       const float* __restrict__ dinv,
                       float2* __restrict__ csr_pack, int E) {
    int e = blockIdx.x * blockDim.x + threadIdx.x;
    if (e < E) {
        const int d = dstv[e];
        const int s = srcv[e];
        const int slot = atomicAdd(&cur[d], 1);
        float2 rec;
        rec.x = __int_as_float(s);
        rec.y = dinv[s] * dinv[d];
        csr_pack[rowptr[d] + slot] = rec;
    }
}

__global__ void k_bounds(const int* __restrict__ batch, int N, int G,
                         int* __restrict__ start) {
    const int g = blockIdx.x * blockDim.x + threadIdx.x;
    if (g > G) return;
    int lo = 0, hi = N;
    while (lo < hi) {
        const int mid = (lo + hi) >> 1;
        if (batch[mid] < g) lo = mid + 1; else hi = mid;
    }
    start[g] = lo;
}

// Wc = W4 @ Wlin (128 x T), bc = b4 @ Wlin + blin (T)
__global__ void k_combine(const float* __restrict__ W4, const float* __restrict__ Wlin,
                          const float* __restrict__ b4, const float* __restrict__ blin,
                          float* __restrict__ Wc, float* __restrict__ bc, int T) {
    const int idx = blockIdx.x * blockDim.x + threadIdx.x;
    if (idx < 128 * T) {
        const int k = idx / T, t = idx % T;
        float acc = 0.f;
        #pragma unroll 8
        for (int j = 0; j < 128; ++j)
            acc = fmaf(W4[k * 128 + j], Wlin[j * T + t], acc);
        Wc[idx] = acc;
    }
    if (idx < T) {
        float acc = blin[idx];
        #pragma unroll 8
        for (int j = 0; j < 128; ++j)
            acc = fmaf(b4[j], Wlin[j * T + idx], acc);
        bc[idx] = acc;
    }
}

__device__ __forceinline__ void fma4(float4& acc, float s, const float4& w) {
    acc.x = fmaf(s, w.x, acc.x);
    acc.y = fmaf(s, w.y, acc.y);
    acc.z = fmaf(s, w.z, acc.z);
    acc.w = fmaf(s, w.w, acc.w);
}

// Gather aggregated rows n0 AND n1, interleaved 4-wide each: 8 independent
// {record -> row} load chains. Branch-free body: rows are padded to x4
// records, and an exhausted row redirects its CHUNK ADDRESS to the dummy
// zero-chunk (one cndmask per row per iter, loads unconditional).
__device__ __forceinline__ void gather_pair2(
    int n0, int n1, int v0, int v1,
    const float* __restrict__ Hin,
    const int* __restrict__ rowptr, const float2* __restrict__ pk,
    const float* __restrict__ dinv, int lane, int dummy,
    float4& r0, float4& r1)
{
    const int nc0 = v0 ? n0 : 0;
    const int nc1 = v1 ? n1 : 0;
    const float dn0 = v0 ? dinv[nc0] : 0.f;
    const float dn1 = v1 ? dinv[nc1] : 0.f;
    int c0 = rowptr[nc0];
    int c1 = rowptr[nc1];
    const int e0 = v0 ? rowptr[nc0 + 1] : c0;
    const int e1 = v1 ? rowptr[nc1 + 1] : c1;

    const float4 s0v = *(const float4*)(Hin + (size_t)nc0 * 128 + 4 * lane);
    const float4 s1v = *(const float4*)(Hin + (size_t)nc1 * 128 + 4 * lane);
    const float sw0 = dn0 * dn0, sw1 = dn1 * dn1;
    float4 p0 = make_float4(s0v.x * sw0, s0v.y * sw0, s0v.z * sw0, s0v.w * sw0);
    float4 q0 = make_float4(s1v.x * sw1, s1v.y * sw1, s1v.z * sw1, s1v.w * sw1);
    float4 p1 = make_float4(0.f, 0.f, 0.f, 0.f);
    float4 q1 = make_float4(0.f, 0.f, 0.f, 0.f);

    while (c0 < e0 || c1 < e1) {
        const int a0 = (c0 < e0) ? c0 : dummy;   // chunk-level select only
        const int a1 = (c1 < e1) ? c1 : dummy;
        const float2 ra0 = pk[a0];
        const float2 ra1 = pk[a0 + 1];
        const float2 ra2 = pk[a0 + 2];
        const float2 ra3 = pk[a0 + 3];
        const float2 rb0 = pk[a1];
        const float2 rb1 = pk[a1 + 1];
        const float2 rb2 = pk[a1 + 2];
        const float2 rb3 = pk[a1 + 3];
        const float4 va0 = *(const float4*)(Hin + (size_t)__float_as_int(ra0.x) * 128 + 4 * lane);
        const float4 va1 = *(const float4*)(Hin + (size_t)__float_as_int(ra1.x) * 128 + 4 * lane);
        const float4 va2 = *(const float4*)(Hin + (size_t)__float_as_int(ra2.x) * 128 + 4 * lane);
        const float4 va3 = *(const float4*)(Hin + (size_t)__float_as_int(ra3.x) * 128 + 4 * lane);
        const float4 vb0 = *(const float4*)(Hin + (size_t)__float_as_int(rb0.x) * 128 + 4 * lane);
        const float4 vb1 = *(const float4*)(Hin + (size_t)__float_as_int(rb1.x) * 128 + 4 * lane);
        const float4 vb2 = *(const float4*)(Hin + (size_t)__float_as_int(rb2.x) * 128 + 4 * lane);
        const float4 vb3 = *(const float4*)(Hin + (size_t)__float_as_int(rb3.x) * 128 + 4 * lane);
        fma4(p0, ra0.y, va0); fma4(p1, ra1.y, va1);
        fma4(p0, ra2.y, va2); fma4(p1, ra3.y, va3);
        fma4(q0, rb0.y, vb0); fma4(q1, rb1.y, vb1);
        fma4(q0, rb2.y, vb2); fma4(q1, rb3.y, vb3);
        c0 += 4; c1 += 4;
    }
    p0.x += p1.x; p0.y += p1.y; p0.z += p1.z; p0.w += p1.w;
    q0.x += q1.x; q0.y += q1.y; q0.z += q1.z; q0.w += q1.w;
    r0 = p0;
    r1 = q0;
}

// Fused layer: Hout[n] = relu( (A·Hin)[n] @ W + bias ). One 32-row tile/block.
// W staged in two 64x128 halves; accumulators live across both passes.
__global__ __launch_bounds__(512, 6) void k_layer(
    const float* __restrict__ Hin, const float* __restrict__ W,
    const float* __restrict__ bias,
    const int* __restrict__ rowptr, const float2* __restrict__ csr_pack,
    const float* __restrict__ dinv, int dummy,
    float* __restrict__ Hout, int N)
{
    __shared__ float Wl[64 * 128];    // 32 KiB: half of W [k][c]
    __shared__ float hl[32 * 128];    // 16 KiB: 32 aggregated rows
    const int tid = threadIdx.x;
    for (int i = tid; i < 2048; i += 512)
        ((float4*)Wl)[i] = ((const float4*)W)[i];          // rows 0..63

    const int lane = tid & 31;
    const int grp  = tid >> 5;        // 0..15
    const int rowBase = blockIdx.x << 5;

    const int n0 = rowBase + grp;
    const int n1 = rowBase + grp + 16;
    const int v0 = n0 < N, v1 = n1 < N;
    float4 g0, g1;
    gather_pair2(n0, n1, v0, v1, Hin, rowptr, csr_pack, dinv, lane, dummy, g0, g1);
    if (v0) *(float4*)(hl + grp * 128 + 4 * lane) = g0;
    if (v1) *(float4*)(hl + (grp + 16) * 128 + 4 * lane) = g1;
    __syncthreads();   // hl + Wl(half 0) ready

    float4 a0 = make_float4(0.f, 0.f, 0.f, 0.f);
    float4 a1 = make_float4(0.f, 0.f, 0.f, 0.f);
    // pass 0: k = 0..63
    #pragma unroll 4
    for (int kq = 0; kq < 16; ++kq) {
        const float4 h0 = *(const float4*)(hl + grp * 128 + 4 * kq);
        const float4 h1 = *(const float4*)(hl + (grp + 16) * 128 + 4 * kq);
        const float4* wp = ((const float4*)Wl) + (4 * kq) * 32 + lane;
        const float4 w0 = wp[0];
        const float4 w1 = wp[32];
        const float4 w2 = wp[64];
        const float4 w3 = wp[96];
        fma4(a0, h0.x, w0); fma4(a0, h0.y, w1); fma4(a0, h0.z, w2); fma4(a0, h0.w, w3);
        fma4(a1, h1.x, w0); fma4(a1, h1.y, w1); fma4(a1, h1.z, w2); fma4(a1, h1.w, w3);
    }
    __syncthreads();   // pass-0 Wl reads done
    for (int i = tid; i < 2048; i += 512)
        ((float4*)Wl)[i] = ((const float4*)(W + 64 * 128))[i];  // rows 64..127
    __syncthreads();   // Wl(half 1) ready
    // pass 1: k = 64..127
    #pragma unroll 4
    for (int kq = 0; kq < 16; ++kq) {
        const float4 h0 = *(const float4*)(hl + grp * 128 + 64 + 4 * kq);
        const float4 h1 = *(const float4*)(hl + (grp + 16) * 128 + 64 + 4 * kq);
        const float4* wp = ((const float4*)Wl) + (4 * kq) * 32 + lane;
        const float4 w0 = wp[0];
        const float4 w1 = wp[32];
        const float4 w2 = wp[64];
        const float4 w3 = wp[96];
        fma4(a0, h0.x, w0); fma4(a0, h0.y, w1); fma4(a0, h0.z, w2); fma4(a0, h0.w, w3);
        fma4(a1, h1.x, w0); fma4(a1, h1.y, w1); fma4(a1, h1.z, w2); fma4(a1, h1.w, w3);
    }

    const float4 bv = ((const float4*)bias)[lane];
    a0.x += bv.x; a0.y += bv.y; a0.z += bv.z; a0.w += bv.w;
    a1.x += bv.x; a1.y += bv.y; a1.z += bv.z; a1.w += bv.w;
    a0.x = fmaxf(a0.x, 0.f); a0.y = fmaxf(a0.y, 0.f);
    a0.z = fmaxf(a0.z, 0.f); a0.w = fmaxf(a0.w, 0.f);
    a1.x = fmaxf(a1.x, 0.f); a1.y = fmaxf(a1.y, 0.f);
    a1.z = fmaxf(a1.z, 0.f); a1.w = fmaxf(a1.w, 0.f);
    if (v0) *(float4*)(Hout + (size_t)n0 * 128 + 4 * lane) = a0;
    if (v1) *(float4*)(Hout + (size_t)n1 * 128 + 4 * lane) = a1;
}

// Layer 4 gather fused with segmented mean-pool numerator (batch sorted).
__global__ __launch_bounds__(512) void k_g4pool(
    const int* __restrict__ rowptr, const float2* __restrict__ csr_pack,
    const float* __restrict__ dinv, const float* __restrict__ Hin,
    const int* __restrict__ batch, const int* __restrict__ startv,
    float* __restrict__ pooled, int dummy, int N)
{
    __shared__ float hl[32][128];   // 16 KiB gathered rows
    __shared__ float red[4][128];   // 2 KiB reduction scratch
    const int tid = threadIdx.x;
    const int lane = tid & 31;
    const int grp  = tid >> 5;      // 0..15
    const int base = blockIdx.x << 5;

    const int n0 = base + 2 * grp;
    const int n1 = n0 + 1;
    float4 r0, r1;
    gather_pair2(n0, n1, n0 < N, n1 < N, Hin, rowptr, csr_pack, dinv, lane, dummy, r0, r1);
    *(float4*)(&hl[2 * grp][4 * lane]) = r0;       // invalid rows -> zeros
    *(float4*)(&hl[2 * grp + 1][4 * lane]) = r1;
    __syncthreads();

    const int g0 = batch[base < N ? base : N - 1];
    const int g1 = batch[(base + 31) < N ? (base + 31) : N - 1];
    const int c = tid & 127;        // channel
    const int q = tid >> 7;         // 0..3
    for (int g = g0; g <= g1; ++g) {
        const int lo = max(startv[g], base);
        const int hi = min(startv[g + 1], base + 32);
        float s = 0.f;
        for (int r = lo - base + q; r < hi - base; r += 4)
            s += hl[r][c];
        red[q][c] = s;
        __syncthreads();
        if (q == 0) {
            const float tot = red[0][c] + red[1][c] + red[2][c] + red[3][c];
            atomicAdd(&pooled[(size_t)g * 128 + c], tot);
        }
        __syncthreads();
    }
}

// out[g][t] = (pooled[g]/cnt[g]) . Wc[:,t] + bc[t]
__global__ void k_final(const float* __restrict__ pooled, const int* __restrict__ startv,
                        const float* __restrict__ Wc, const float* __restrict__ bc,
                        float* __restrict__ out, int T)
{
    __shared__ float hv[128];
    const int g = blockIdx.x;
    const int c = threadIdx.x;
    const float inv = 1.0f / fmaxf((float)(startv[g + 1] - startv[g]), 1.0f);
    hv[c] = pooled[(size_t)g * 128 + c] * inv;
    __syncthreads();
    if (c < T) {
        float acc = bc[c];
        #pragma unroll
        for (int k = 0; k < 128; ++k)
            acc = fmaf(hv[k], Wc[k * T + c], acc);
        out[g * T + c] = acc;
    }
}

extern "C" void kernel_launch(void* const* d_in, const int* in_sizes, int n_in,
                              void* d_out, int out_size, void* d_ws, size_t ws_size,
                              hipStream_t stream)
{
    const float* x     = (const float*)d_in[0];
    const int*   ei    = (const int*)d_in[1];
    const int*   batch = (const int*)d_in[2];
    const float* W1    = (const float*)d_in[3];
    const float* b1    = (const float*)d_in[4];
    const float* Ws    = (const float*)d_in[5];
    const float* bs    = (const float*)d_in[6];
    const float* Wlin  = (const float*)d_in[7];
    const float* blin  = (const float*)d_in[8];
    float* out = (float*)d_out;

    const int N = in_sizes[0] / 128;
    const int E = in_sizes[1] / 2;
    const int T = in_sizes[8];           // 10
    const int G = out_size / T;          // 512

    const int packCap = E + 3 * N + 4;   // padded records + dummy chunk
    const int dummy   = E + 3 * N;       // 4 zero records live here

    // workspace layout (float offsets):
    float*  ws = (float*)d_ws;
    int*    cnt      = (int*)ws;                     // [N] histogram -> cursor (dead after fill)
    int*    rowptr   = (int*)(ws + 50000);           // [N+1]
    int*    bsums    = (int*)(ws + 100016);          // [256]
    int*    start    = (int*)(ws + 100272);          // [G+1]
    float2* csr_pack = (float2*)(ws + 100800);       // [packCap]
    float*  dinv     = ws + 1680816;                 // [N]
    float*  bufA     = ws + 1730816;                 // [N*128]
    float*  bufB     = ws + 8130816;                 // [N*128]
    float*  pooled   = ws + 14530816;                // [G*128]
    float*  Wc       = ws + 24000;                   // reuse cnt region (dead), [128*T]
    float*  bc       = ws + 24000 + 128 * 10;        // [T]

    const int* srcs = ei;
    const int* dsts = ei + E;
    const float* W4 = Ws + 2 * 16384;
    const float* b4 = bs + 2 * 128;

    hipMemsetAsync(cnt, 0, (size_t)N * sizeof(int), stream);
    hipMemsetAsync(csr_pack, 0, (size_t)packCap * sizeof(float2), stream);
    hipMemsetAsync(pooled, 0, (size_t)G * 128 * sizeof(float), stream);

    const int nb = (N + 255) / 256;
    k_count <<<(E + 255) / 256, 256, 0, stream>>>(dsts, E, cnt);
    k_scan1 <<<nb, 256, 0, stream>>>(cnt, N, rowptr, bsums, dinv);
    k_scan2 <<<1, 256, 0, stream>>>(bsums, nb);
    k_scan3 <<<nb, 256, 0, stream>>>(rowptr, bsums, cnt, N);
    k_fill  <<<(E + 255) / 256, 256, 0, stream>>>(srcs, dsts, rowptr, cnt, dinv, csr_pack, E);
    k_bounds<<<(G + 256) / 256, 256, 0, stream>>>(batch, N, G, start);
    // cnt region dead from here; Wc/bc overlap it (k_combine runs after k_fill)
    k_combine<<<(128 * T + 255) / 256, 256, 0, stream>>>(W4, Wlin, b4, blin, Wc, bc, T);

    const int layerBlocks = (N + 31) / 32;   // 1563, one 32-row tile each

    k_layer<<<layerBlocks, 512, 0, stream>>>(x,    W1,         b1,       rowptr, csr_pack, dinv, dummy, bufA, N);
    k_layer<<<layerBlocks, 512, 0, stream>>>(bufA, Ws,         bs,       rowptr, csr_pack, dinv, dummy, bufB, N);
    k_layer<<<layerBlocks, 512, 0, stream>>>(bufB, Ws + 16384, bs + 128, rowptr, csr_pack, dinv, dummy, bufA, N);
    // layer 4 gather fused with pool
    k_g4pool<<<layerBlocks, 512, 0, stream>>>(rowptr, csr_pack, dinv, bufA, batch, start, pooled, dummy, N);

    k_final<<<G, 128, 0, stream>>>(pooled, start, Wc, bc, out, T);
}